// Round 2
// baseline (3063.916 us; speedup 1.0000x reference)
//
#include <hip/hip_runtime.h>

typedef __attribute__((ext_vector_type(8))) short bf16x8;
typedef __attribute__((ext_vector_type(4))) float f32x4;

#define D_EMB 2048
#define NQ    256
#define NB    4
#define NS    2048
#define NH    16
#define HK    128
#define FF    8192

__device__ __forceinline__ float b2f(short s) {
  union { unsigned int u; float f; } c;
  c.u = ((unsigned int)(unsigned short)s) << 16;
  return c.f;
}
__device__ __forceinline__ short f2b(float f) {
  union { float f; unsigned int u; } c; c.f = f;
  unsigned int u = c.u;
  u += 0x7FFFu + ((u >> 16) & 1u);   // RNE
  return (short)(u >> 16);
}

// ---------------- LayerNorm (row = 2048), fp32 in -> bf16 out ----------------
__global__ __launch_bounds__(256)
void ln_kernel(const float* __restrict__ x, const float* __restrict__ scale,
               const float* __restrict__ offset, short* __restrict__ out) {
  const int row = blockIdx.x, tid = threadIdx.x;
  const float* xr = x + (size_t)row * D_EMB + tid * 8;
  f32x4 v0 = *(const f32x4*)xr;
  f32x4 v1 = *(const f32x4*)(xr + 4);
  float f[8], s = 0.f, sq = 0.f;
#pragma unroll
  for (int i = 0; i < 4; ++i) { f[i] = v0[i]; f[4 + i] = v1[i]; }
#pragma unroll
  for (int i = 0; i < 8; ++i) { s += f[i]; sq += f[i] * f[i]; }
#pragma unroll
  for (int off = 1; off < 64; off <<= 1) {
    s  += __shfl_xor(s, off, 64);
    sq += __shfl_xor(sq, off, 64);
  }
  __shared__ float red[2][4];
  const int w = tid >> 6;
  if ((tid & 63) == 0) { red[0][w] = s; red[1][w] = sq; }
  __syncthreads();
  s  = red[0][0] + red[0][1] + red[0][2] + red[0][3];
  sq = red[1][0] + red[1][1] + red[1][2] + red[1][3];
  const float mu  = s * (1.f / D_EMB);
  const float var = sq * (1.f / D_EMB) - mu * mu;
  const float inv = rsqrtf(var + 1e-5f);
  bf16x8 ov;
#pragma unroll
  for (int i = 0; i < 8; ++i) {
    const int c = tid * 8 + i;
    ov[i] = f2b((f[i] - mu) * inv * scale[c] + offset[c]);
  }
  *(bf16x8*)(out + (size_t)row * D_EMB + tid * 8) = ov;
}

// ---------------- GEMM: C = A[M,Kd] @ W[Kd,N] + bias, epilogue ----------------
// EPI: 0 = bias, 1 = bias+residual(fp32), 2 = bias+gelu(exact)
// ABF: 1 = A is bf16 (ws), 0 = A is fp32 (input tensors)
// OUTF: 1 = fp32 output, 0 = bf16 output
template<int EPI, int ABF, int OUTF>
__global__ __launch_bounds__(256)
void gemm_kernel(const void* __restrict__ Ap, const float* __restrict__ W,
                 const float* __restrict__ bias, const float* __restrict__ res,
                 void* __restrict__ Cp, int M, int N, int Kd) {
  __shared__ short ldsA[128][32];
  __shared__ short ldsB[128][32];   // transposed: [n][k]
  const int tid = threadIdx.x;
  const int m0 = blockIdx.y * 128, n0 = blockIdx.x * 128;
  const int w = tid >> 6, lane = tid & 63, l15 = lane & 15, quad = lane >> 4;
  const int wr = (w >> 1) * 64, wc = (w & 1) * 64;
  f32x4 acc[4][4];
#pragma unroll
  for (int mi = 0; mi < 4; ++mi)
#pragma unroll
    for (int ni = 0; ni < 4; ++ni) acc[mi][ni] = (f32x4){0.f, 0.f, 0.f, 0.f};

  for (int k0 = 0; k0 < Kd; k0 += 32) {
    __syncthreads();
#pragma unroll
    for (int p = 0; p < 2; ++p) {
      const int idx = p * 256 + tid;
      {   // A tile: 128 x 32
        const int r = idx >> 2, c0 = (idx & 3) * 8;
        if (ABF) {
          const short* A = (const short*)Ap;
          *(bf16x8*)&ldsA[r][c0] =
              *(const bf16x8*)(A + (size_t)(m0 + r) * Kd + k0 + c0);
        } else {
          const float* A = (const float*)Ap;
          const float* p4 = A + (size_t)(m0 + r) * Kd + k0 + c0;
          f32x4 a = *(const f32x4*)p4, b = *(const f32x4*)(p4 + 4);
          bf16x8 t;
#pragma unroll
          for (int i = 0; i < 4; ++i) { t[i] = f2b(a[i]); t[4 + i] = f2b(b[i]); }
          *(bf16x8*)&ldsA[r][c0] = t;
        }
      }
      {   // B tile: 32 x 128 fp32, convert + store transposed
        const int r = idx >> 4, c0 = (idx & 15) * 8;
        const float* p4 = W + (size_t)(k0 + r) * N + n0 + c0;
        f32x4 a = *(const f32x4*)p4, b = *(const f32x4*)(p4 + 4);
#pragma unroll
        for (int i = 0; i < 4; ++i) {
          ldsB[c0 + i][r]     = f2b(a[i]);
          ldsB[c0 + 4 + i][r] = f2b(b[i]);
        }
      }
    }
    __syncthreads();
    bf16x8 af[4], bfr[4];
#pragma unroll
    for (int mi = 0; mi < 4; ++mi)
      af[mi] = *(bf16x8*)&ldsA[wr + mi * 16 + l15][quad * 8];
#pragma unroll
    for (int ni = 0; ni < 4; ++ni)
      bfr[ni] = *(bf16x8*)&ldsB[wc + ni * 16 + l15][quad * 8];
#pragma unroll
    for (int mi = 0; mi < 4; ++mi)
#pragma unroll
      for (int ni = 0; ni < 4; ++ni)
        acc[mi][ni] = __builtin_amdgcn_mfma_f32_16x16x32_bf16(
            af[mi], bfr[ni], acc[mi][ni], 0, 0, 0);
  }

#pragma unroll
  for (int mi = 0; mi < 4; ++mi) {
#pragma unroll
    for (int ni = 0; ni < 4; ++ni) {
      const int gn = n0 + wc + ni * 16 + l15;
      const float bv = bias[gn];
#pragma unroll
      for (int r = 0; r < 4; ++r) {
        const int gm = m0 + wr + mi * 16 + quad * 4 + r;
        float v = acc[mi][ni][r] + bv;
        if (EPI == 1) v += res[(size_t)gm * N + gn];
        if (EPI == 2) v = 0.5f * v * (1.f + erff(v * 0.70710678118654752f));
        if (OUTF) ((float*)Cp)[(size_t)gm * N + gn] = v;
        else      ((short*)Cp)[(size_t)gm * N + gn] = f2b(v);
      }
    }
  }
}

// ---------------- Flash cross-attention with extra learned kv position ----------------
// grid: NB*NH*4 blocks; block handles 64 q rows for one (b,h); wave w: 16 rows.
__global__ __launch_bounds__(256)
void attn_kernel(const short* __restrict__ qh, const short* __restrict__ kh,
                 const short* __restrict__ vh, const float* __restrict__ bias_k,
                 const float* __restrict__ bias_v, short* __restrict__ ctx) {
  const int bx = blockIdx.x;
  const int b = bx >> 6;            // / (NH*4)
  const int h = (bx >> 2) & 15;
  const int qt = bx & 3;
  const int tid = threadIdx.x, w = tid >> 6, lane = tid & 63;
  const int l15 = lane & 15, quad = lane >> 4;
  const int q0 = qt * 64 + w * 16;

  __shared__ short ldsK[32][128];
  __shared__ short ldsV[128][32];        // transposed [d][t]
  __shared__ short ldsP[4][16][32];
  __shared__ float ldsE[4][16];

  const float sc = 0.08838834764831845f;   // 1/sqrt(128)

  bf16x8 aq[4];
  {
    const short* qrow = qh + ((size_t)(b * 256 + q0 + l15)) * D_EMB + h * 128;
#pragma unroll
    for (int s = 0; s < 4; ++s)
      aq[s] = *(const bf16x8*)(qrow + s * 32 + quad * 8);
  }

  f32x4 o[8];
  float m_run[4], l_run[4];
#pragma unroll
  for (int dt = 0; dt < 8; ++dt) o[dt] = (f32x4){0.f, 0.f, 0.f, 0.f};
#pragma unroll
  for (int r = 0; r < 4; ++r) { m_run[r] = -INFINITY; l_run[r] = 0.f; }

  for (int t0 = 0; t0 < NS; t0 += 32) {
    __syncthreads();
#pragma unroll
    for (int p = 0; p < 2; ++p) {
      const int idx = p * 256 + tid;
      const int row = idx >> 4, c0 = (idx & 15) * 8;
      const size_t base = ((size_t)(b * NS + t0 + row)) * D_EMB + h * 128 + c0;
      *(bf16x8*)&ldsK[row][c0] = *(const bf16x8*)(kh + base);
      bf16x8 vv = *(const bf16x8*)(vh + base);
#pragma unroll
      for (int i = 0; i < 8; ++i) ldsV[c0 + i][row] = vv[i];
    }
    __syncthreads();

    f32x4 s0 = (f32x4){0.f, 0.f, 0.f, 0.f}, s1 = (f32x4){0.f, 0.f, 0.f, 0.f};
#pragma unroll
    for (int s = 0; s < 4; ++s) {
      bf16x8 k0f = *(bf16x8*)&ldsK[l15][s * 32 + quad * 8];
      bf16x8 k1f = *(bf16x8*)&ldsK[16 + l15][s * 32 + quad * 8];
      s0 = __builtin_amdgcn_mfma_f32_16x16x32_bf16(aq[s], k0f, s0, 0, 0, 0);
      s1 = __builtin_amdgcn_mfma_f32_16x16x32_bf16(aq[s], k1f, s1, 0, 0, 0);
    }

    float alpha_r[4];
#pragma unroll
    for (int r = 0; r < 4; ++r) {
      const float v0 = s0[r] * sc, v1 = s1[r] * sc;
      float mx = fmaxf(v0, v1);
#pragma unroll
      for (int off = 1; off < 16; off <<= 1) mx = fmaxf(mx, __shfl_xor(mx, off, 16));
      const float m_new = fmaxf(m_run[r], mx);
      const float p0 = expf(v0 - m_new), p1 = expf(v1 - m_new);
      float rs = p0 + p1;
#pragma unroll
      for (int off = 1; off < 16; off <<= 1) rs += __shfl_xor(rs, off, 16);
      alpha_r[r] = expf(m_run[r] - m_new);
      l_run[r] = l_run[r] * alpha_r[r] + rs;
      m_run[r] = m_new;
      ldsP[w][quad * 4 + r][l15]      = f2b(p0);
      ldsP[w][quad * 4 + r][16 + l15] = f2b(p1);
    }
#pragma unroll
    for (int dt = 0; dt < 8; ++dt)
#pragma unroll
      for (int r = 0; r < 4; ++r) o[dt][r] *= alpha_r[r];
    __syncthreads();

    bf16x8 pf = *(bf16x8*)&ldsP[w][l15][quad * 8];
#pragma unroll
    for (int dt = 0; dt < 8; ++dt) {
      bf16x8 vf = *(bf16x8*)&ldsV[dt * 16 + l15][quad * 8];
      o[dt] = __builtin_amdgcn_mfma_f32_16x16x32_bf16(pf, vf, o[dt], 0, 0, 0);
    }
  }

  // extra learned kv position (t = NS)
  if (lane < 16) {
    const short* qp = qh + ((size_t)(b * 256 + q0 + lane)) * D_EMB + h * 128;
    const float* bk = bias_k + h * 128;
    float le = 0.f;
    for (int d = 0; d < 128; ++d) le += b2f(qp[d]) * bk[d];
    ldsE[w][lane] = le * sc;
  }
  __syncthreads();
  float pe_r[4], al_r[4];
#pragma unroll
  for (int r = 0; r < 4; ++r) {
    const float lr = ldsE[w][quad * 4 + r];
    const float m_new = fmaxf(m_run[r], lr);
    pe_r[r] = expf(lr - m_new);
    al_r[r] = expf(m_run[r] - m_new);
    l_run[r] = l_run[r] * al_r[r] + pe_r[r];
  }
#pragma unroll
  for (int dt = 0; dt < 8; ++dt) {
    const float bv = bias_v[h * 128 + dt * 16 + l15];
#pragma unroll
    for (int r = 0; r < 4; ++r) o[dt][r] = o[dt][r] * al_r[r] + pe_r[r] * bv;
  }
#pragma unroll
  for (int dt = 0; dt < 8; ++dt)
#pragma unroll
    for (int r = 0; r < 4; ++r) {
      const size_t row = (size_t)(b * 256 + q0 + quad * 4 + r);
      ctx[row * D_EMB + h * 128 + dt * 16 + l15] = f2b(o[dt][r] / l_run[r]);
    }
}

extern "C" void kernel_launch(void* const* d_in, const int* in_sizes, int n_in,
                              void* d_out, int out_size, void* d_ws, size_t ws_size,
                              hipStream_t stream) {
  const float* x   = (const float*)d_in[0];
  const float* xf1 = (const float*)d_in[1];
  const float* xf2 = (const float*)d_in[2];
  // layer i param base: 3 + (i-1)*12; offsets: ln_s, ln_o, wq, bq, wk, bk, wv, bv, wo, bo, bias_k, bias_v
  const float* L1[12]; const float* L2[12];
  for (int j = 0; j < 12; ++j) { L1[j] = (const float*)d_in[3 + j]; L2[j] = (const float*)d_in[15 + j]; }
  const float* ln_mlp_s = (const float*)d_in[27];
  const float* ln_mlp_o = (const float*)d_in[28];
  const float* w_fc1    = (const float*)d_in[29];
  const float* b_fc1    = (const float*)d_in[30];
  const float* w_fc2    = (const float*)d_in[31];
  const float* b_fc2    = (const float*)d_in[32];
  float* out = (float*)d_out;

  const size_t SZ_XQ  = (size_t)NB * NQ * D_EMB;   // 2M elems
  const size_t SZ_KV  = (size_t)NB * NS * D_EMB;   // 16.8M elems
  const size_t SZ_FC1 = (size_t)NB * NQ * FF;      // 8.4M elems
  float* x1   = (float*)d_ws;          // fp32 intermediates first
  float* x2   = x1 + SZ_XQ;
  short* h_ln = (short*)(x2 + SZ_XQ);  // bf16 intermediates
  short* qh   = h_ln + SZ_XQ;
  short* ctxb = qh + SZ_XQ;
  short* fc1  = ctxb + SZ_XQ;
  short* kh   = fc1 + SZ_FC1;
  short* vh   = kh + SZ_KV;

  const dim3 blk(256);
  const dim3 g_q(D_EMB / 128, (NB * NQ) / 128);    // (16, 8)
  const dim3 g_kv(D_EMB / 128, (NB * NS) / 128);   // (16, 64)
  const dim3 g_f1(FF / 128, (NB * NQ) / 128);      // (64, 8)

  // ---- layer 1 ----
  ln_kernel<<<NB * NQ, blk, 0, stream>>>(x, L1[0], L1[1], h_ln);
  gemm_kernel<0,1,0><<<g_q,  blk, 0, stream>>>(h_ln, L1[2], L1[3], nullptr, qh, NB * NQ, D_EMB, D_EMB);
  gemm_kernel<0,0,0><<<g_kv, blk, 0, stream>>>(xf1,  L1[4], L1[5], nullptr, kh, NB * NS, D_EMB, D_EMB);
  gemm_kernel<0,0,0><<<g_kv, blk, 0, stream>>>(xf1,  L1[6], L1[7], nullptr, vh, NB * NS, D_EMB, D_EMB);
  attn_kernel<<<NB * NH * 4, blk, 0, stream>>>(qh, kh, vh, L1[10], L1[11], ctxb);
  gemm_kernel<1,1,1><<<g_q,  blk, 0, stream>>>(ctxb, L1[8], L1[9], x, x1, NB * NQ, D_EMB, D_EMB);

  // ---- layer 2 ----
  ln_kernel<<<NB * NQ, blk, 0, stream>>>(x1, L2[0], L2[1], h_ln);
  gemm_kernel<0,1,0><<<g_q,  blk, 0, stream>>>(h_ln, L2[2], L2[3], nullptr, qh, NB * NQ, D_EMB, D_EMB);
  gemm_kernel<0,0,0><<<g_kv, blk, 0, stream>>>(xf2,  L2[4], L2[5], nullptr, kh, NB * NS, D_EMB, D_EMB);
  gemm_kernel<0,0,0><<<g_kv, blk, 0, stream>>>(xf2,  L2[6], L2[7], nullptr, vh, NB * NS, D_EMB, D_EMB);
  attn_kernel<<<NB * NH * 4, blk, 0, stream>>>(qh, kh, vh, L2[10], L2[11], ctxb);
  gemm_kernel<1,1,1><<<g_q,  blk, 0, stream>>>(ctxb, L2[8], L2[9], x1, x2, NB * NQ, D_EMB, D_EMB);

  // ---- MLP ----
  ln_kernel<<<NB * NQ, blk, 0, stream>>>(x2, ln_mlp_s, ln_mlp_o, h_ln);
  gemm_kernel<2,1,0><<<g_f1, blk, 0, stream>>>(h_ln, w_fc1, b_fc1, nullptr, fc1, NB * NQ, FF, D_EMB);
  gemm_kernel<1,1,1><<<g_q,  blk, 0, stream>>>(fc1, w_fc2, b_fc2, x2, out, NB * NQ, D_EMB, FF);
}

// Round 3
// 1629.546 us; speedup vs baseline: 1.8802x; 1.8802x over previous
//
#include <hip/hip_runtime.h>

typedef __attribute__((ext_vector_type(8))) short bf16x8;
typedef __attribute__((ext_vector_type(4))) float f32x4;

#define D_EMB 2048
#define NQ    256
#define NB    4
#define NS    2048
#define NH    16
#define HK    128
#define FF    8192

__device__ __forceinline__ float b2f(short s) {
  union { unsigned int u; float f; } c;
  c.u = ((unsigned int)(unsigned short)s) << 16;
  return c.f;
}
__device__ __forceinline__ short f2b(float f) {
  union { float f; unsigned int u; } c; c.f = f;
  unsigned int u = c.u;
  u += 0x7FFFu + ((u >> 16) & 1u);   // RNE
  return (short)(u >> 16);
}
__device__ __forceinline__ void gload_lds16(const short* g, short* l) {
  __builtin_amdgcn_global_load_lds(
      (const __attribute__((address_space(1))) void*)g,
      (__attribute__((address_space(3))) void*)l, 16, 0, 0);
}

// ---------------- elementwise fp32 -> bf16 ----------------
__global__ __launch_bounds__(256)
void cvt_kernel(const float* __restrict__ in, short* __restrict__ out, int n8) {
  const int i = (blockIdx.x * 256 + threadIdx.x) * 8;
  if (i >= n8) return;
  f32x4 a = *(const f32x4*)(in + i), b = *(const f32x4*)(in + i + 4);
  bf16x8 t;
#pragma unroll
  for (int j = 0; j < 4; ++j) { t[j] = f2b(a[j]); t[4 + j] = f2b(b[j]); }
  *(bf16x8*)(out + i) = t;
}

// ---------------- W[Kd,N] fp32 -> Wt[N,Kd] bf16 (64x64 tiles) ----------------
__global__ __launch_bounds__(256)
void transpose_kernel(const float* __restrict__ W, short* __restrict__ Wt,
                      int Kd, int N) {
  __shared__ short tile[64][65];   // [n][k]
  const int k0 = blockIdx.y * 64, n0 = blockIdx.x * 64;
  const int tid = threadIdx.x;
  const int r = tid >> 2, c4 = (tid & 3) * 16;
#pragma unroll
  for (int i = 0; i < 16; i += 4) {
    f32x4 v = *(const f32x4*)(W + (size_t)(k0 + r) * N + n0 + c4 + i);
#pragma unroll
    for (int j = 0; j < 4; ++j) tile[c4 + i + j][r] = f2b(v[j]);
  }
  __syncthreads();
  // write rows of Wt: n = n0 + r, k = k0 + c4 .. +15
  bf16x8 o0, o1;
#pragma unroll
  for (int j = 0; j < 8; ++j) { o0[j] = tile[r][c4 + j]; o1[j] = tile[r][c4 + 8 + j]; }
  short* dst = Wt + (size_t)(n0 + r) * Kd + k0 + c4;
  *(bf16x8*)dst = o0;
  *(bf16x8*)(dst + 8) = o1;
}

// ---------------- LayerNorm (row = 2048), fp32 in -> bf16 out ----------------
__global__ __launch_bounds__(256)
void ln_kernel(const float* __restrict__ x, const float* __restrict__ scale,
               const float* __restrict__ offset, short* __restrict__ out) {
  const int row = blockIdx.x, tid = threadIdx.x;
  const float* xr = x + (size_t)row * D_EMB + tid * 8;
  f32x4 v0 = *(const f32x4*)xr;
  f32x4 v1 = *(const f32x4*)(xr + 4);
  float f[8], s = 0.f, sq = 0.f;
#pragma unroll
  for (int i = 0; i < 4; ++i) { f[i] = v0[i]; f[4 + i] = v1[i]; }
#pragma unroll
  for (int i = 0; i < 8; ++i) { s += f[i]; sq += f[i] * f[i]; }
#pragma unroll
  for (int off = 1; off < 64; off <<= 1) {
    s  += __shfl_xor(s, off, 64);
    sq += __shfl_xor(sq, off, 64);
  }
  __shared__ float red[2][4];
  const int w = tid >> 6;
  if ((tid & 63) == 0) { red[0][w] = s; red[1][w] = sq; }
  __syncthreads();
  s  = red[0][0] + red[0][1] + red[0][2] + red[0][3];
  sq = red[1][0] + red[1][1] + red[1][2] + red[1][3];
  const float mu  = s * (1.f / D_EMB);
  const float var = sq * (1.f / D_EMB) - mu * mu;
  const float inv = rsqrtf(var + 1e-5f);
  bf16x8 ov;
#pragma unroll
  for (int i = 0; i < 8; ++i) {
    const int c = tid * 8 + i;
    ov[i] = f2b((f[i] - mu) * inv * scale[c] + offset[c]);
  }
  *(bf16x8*)(out + (size_t)row * D_EMB + tid * 8) = ov;
}

// ---------------- GEMM (m97 style): C = A[M,Kd] @ Wt[N,Kd]^T + bias ----------------
// EPI: 0 = bias, 1 = bias+residual(fp32), 2 = bias+gelu(exact)
// OUTF: 1 = fp32 output, 0 = bf16 output
template<int EPI, int OUTF>
__global__ __launch_bounds__(256)
void gemm_kernel(const short* __restrict__ A, const short* __restrict__ Bt,
                 const float* __restrict__ bias, const float* __restrict__ res,
                 void* __restrict__ Cp, int M, int N, int Kd) {
  __shared__ short ldsA[128 * 32];
  __shared__ short ldsB[128 * 32];
  const int tid = threadIdx.x;
  const int m0 = blockIdx.y * 128, n0 = blockIdx.x * 128;
  const int w = tid >> 6, lane = tid & 63, l15 = lane & 15, quad = lane >> 4;
  const int wr = (w >> 1) * 64, wc = (w & 1) * 64;
  const int sr = tid >> 2;           // 0..63 staging row
  const int sc = (tid & 3) * 8;      // staging col (elements)
  f32x4 acc[4][4];
#pragma unroll
  for (int mi = 0; mi < 4; ++mi)
#pragma unroll
    for (int ni = 0; ni < 4; ++ni) acc[mi][ni] = (f32x4){0.f, 0.f, 0.f, 0.f};

  const short* pa0 = A  + (size_t)(m0 + sr) * Kd + sc;
  const short* pa1 = A  + (size_t)(m0 + 64 + sr) * Kd + sc;
  const short* pb0 = Bt + (size_t)(n0 + sr) * Kd + sc;
  const short* pb1 = Bt + (size_t)(n0 + 64 + sr) * Kd + sc;

  for (int k0 = 0; k0 < Kd; k0 += 32) {
    __syncthreads();
    gload_lds16(pa0 + k0, ldsA + tid * 8);
    gload_lds16(pa1 + k0, ldsA + 2048 + tid * 8);
    gload_lds16(pb0 + k0, ldsB + tid * 8);
    gload_lds16(pb1 + k0, ldsB + 2048 + tid * 8);
    __syncthreads();
    bf16x8 af[4], bfr[4];
#pragma unroll
    for (int mi = 0; mi < 4; ++mi)
      af[mi] = *(bf16x8*)&ldsA[(wr + mi * 16 + l15) * 32 + quad * 8];
#pragma unroll
    for (int ni = 0; ni < 4; ++ni)
      bfr[ni] = *(bf16x8*)&ldsB[(wc + ni * 16 + l15) * 32 + quad * 8];
#pragma unroll
    for (int mi = 0; mi < 4; ++mi)
#pragma unroll
      for (int ni = 0; ni < 4; ++ni)
        acc[mi][ni] = __builtin_amdgcn_mfma_f32_16x16x32_bf16(
            af[mi], bfr[ni], acc[mi][ni], 0, 0, 0);
  }

#pragma unroll
  for (int mi = 0; mi < 4; ++mi) {
#pragma unroll
    for (int ni = 0; ni < 4; ++ni) {
      const int gn = n0 + wc + ni * 16 + l15;
      const float bv = bias[gn];
#pragma unroll
      for (int r = 0; r < 4; ++r) {
        const int gm = m0 + wr + mi * 16 + quad * 4 + r;
        float v = acc[mi][ni][r] + bv;
        if (EPI == 1) v += res[(size_t)gm * N + gn];
        if (EPI == 2) v = 0.5f * v * (1.f + erff(v * 0.70710678118654752f));
        if (OUTF) ((float*)Cp)[(size_t)gm * N + gn] = v;
        else      ((short*)Cp)[(size_t)gm * N + gn] = f2b(v);
      }
    }
  }
}

// ---------------- Flash cross-attention with extra learned kv position ----------------
__global__ __launch_bounds__(256)
void attn_kernel(const short* __restrict__ qh, const short* __restrict__ kh,
                 const short* __restrict__ vh, const float* __restrict__ bias_k,
                 const float* __restrict__ bias_v, short* __restrict__ ctx) {
  const int bx = blockIdx.x;
  const int b = bx >> 6;
  const int h = (bx >> 2) & 15;
  const int qt = bx & 3;
  const int tid = threadIdx.x, w = tid >> 6, lane = tid & 63;
  const int l15 = lane & 15, quad = lane >> 4;
  const int q0 = qt * 64 + w * 16;

  __shared__ short ldsK[32][128];
  __shared__ short ldsV[128][32];
  __shared__ short ldsP[4][16][32];
  __shared__ float ldsE[4][16];

  const float sc = 0.08838834764831845f;

  bf16x8 aq[4];
  {
    const short* qrow = qh + ((size_t)(b * 256 + q0 + l15)) * D_EMB + h * 128;
#pragma unroll
    for (int s = 0; s < 4; ++s)
      aq[s] = *(const bf16x8*)(qrow + s * 32 + quad * 8);
  }

  f32x4 o[8];
  float m_run[4], l_run[4];
#pragma unroll
  for (int dt = 0; dt < 8; ++dt) o[dt] = (f32x4){0.f, 0.f, 0.f, 0.f};
#pragma unroll
  for (int r = 0; r < 4; ++r) { m_run[r] = -INFINITY; l_run[r] = 0.f; }

  for (int t0 = 0; t0 < NS; t0 += 32) {
    __syncthreads();
#pragma unroll
    for (int p = 0; p < 2; ++p) {
      const int idx = p * 256 + tid;
      const int row = idx >> 4, c0 = (idx & 15) * 8;
      const size_t base = ((size_t)(b * NS + t0 + row)) * D_EMB + h * 128 + c0;
      *(bf16x8*)&ldsK[row][c0] = *(const bf16x8*)(kh + base);
      bf16x8 vv = *(const bf16x8*)(vh + base);
#pragma unroll
      for (int i = 0; i < 8; ++i) ldsV[c0 + i][row] = vv[i];
    }
    __syncthreads();

    f32x4 s0 = (f32x4){0.f, 0.f, 0.f, 0.f}, s1 = (f32x4){0.f, 0.f, 0.f, 0.f};
#pragma unroll
    for (int s = 0; s < 4; ++s) {
      bf16x8 k0f = *(bf16x8*)&ldsK[l15][s * 32 + quad * 8];
      bf16x8 k1f = *(bf16x8*)&ldsK[16 + l15][s * 32 + quad * 8];
      s0 = __builtin_amdgcn_mfma_f32_16x16x32_bf16(aq[s], k0f, s0, 0, 0, 0);
      s1 = __builtin_amdgcn_mfma_f32_16x16x32_bf16(aq[s], k1f, s1, 0, 0, 0);
    }

    float alpha_r[4];
#pragma unroll
    for (int r = 0; r < 4; ++r) {
      const float v0 = s0[r] * sc, v1 = s1[r] * sc;
      float mx = fmaxf(v0, v1);
#pragma unroll
      for (int off = 1; off < 16; off <<= 1) mx = fmaxf(mx, __shfl_xor(mx, off, 16));
      const float m_new = fmaxf(m_run[r], mx);
      const float p0 = expf(v0 - m_new), p1 = expf(v1 - m_new);
      float rs = p0 + p1;
#pragma unroll
      for (int off = 1; off < 16; off <<= 1) rs += __shfl_xor(rs, off, 16);
      alpha_r[r] = expf(m_run[r] - m_new);
      l_run[r] = l_run[r] * alpha_r[r] + rs;
      m_run[r] = m_new;
      ldsP[w][quad * 4 + r][l15]      = f2b(p0);
      ldsP[w][quad * 4 + r][16 + l15] = f2b(p1);
    }
#pragma unroll
    for (int dt = 0; dt < 8; ++dt)
#pragma unroll
      for (int r = 0; r < 4; ++r) o[dt][r] *= alpha_r[r];
    __syncthreads();

    bf16x8 pf = *(bf16x8*)&ldsP[w][l15][quad * 8];
#pragma unroll
    for (int dt = 0; dt < 8; ++dt) {
      bf16x8 vf = *(bf16x8*)&ldsV[dt * 16 + l15][quad * 8];
      o[dt] = __builtin_amdgcn_mfma_f32_16x16x32_bf16(pf, vf, o[dt], 0, 0, 0);
    }
  }

  if (lane < 16) {
    const short* qp = qh + ((size_t)(b * 256 + q0 + lane)) * D_EMB + h * 128;
    const float* bk = bias_k + h * 128;
    float le = 0.f;
    for (int d = 0; d < 128; ++d) le += b2f(qp[d]) * bk[d];
    ldsE[w][lane] = le * sc;
  }
  __syncthreads();
  float pe_r[4], al_r[4];
#pragma unroll
  for (int r = 0; r < 4; ++r) {
    const float lr = ldsE[w][quad * 4 + r];
    const float m_new = fmaxf(m_run[r], lr);
    pe_r[r] = expf(lr - m_new);
    al_r[r] = expf(m_run[r] - m_new);
    l_run[r] = l_run[r] * al_r[r] + pe_r[r];
  }
#pragma unroll
  for (int dt = 0; dt < 8; ++dt) {
    const float bv = bias_v[h * 128 + dt * 16 + l15];
#pragma unroll
    for (int r = 0; r < 4; ++r) o[dt][r] = o[dt][r] * al_r[r] + pe_r[r] * bv;
  }
#pragma unroll
  for (int dt = 0; dt < 8; ++dt)
#pragma unroll
    for (int r = 0; r < 4; ++r) {
      const size_t row = (size_t)(b * 256 + q0 + quad * 4 + r);
      ctx[row * D_EMB + h * 128 + dt * 16 + l15] = f2b(o[dt][r] / l_run[r]);
    }
}

extern "C" void kernel_launch(void* const* d_in, const int* in_sizes, int n_in,
                              void* d_out, int out_size, void* d_ws, size_t ws_size,
                              hipStream_t stream) {
  const float* x   = (const float*)d_in[0];
  const float* xf1 = (const float*)d_in[1];
  const float* xf2 = (const float*)d_in[2];
  const float* L1[12]; const float* L2[12];
  for (int j = 0; j < 12; ++j) { L1[j] = (const float*)d_in[3 + j]; L2[j] = (const float*)d_in[15 + j]; }
  const float* ln_mlp_s = (const float*)d_in[27];
  const float* ln_mlp_o = (const float*)d_in[28];
  const float* w_fc1    = (const float*)d_in[29];
  const float* b_fc1    = (const float*)d_in[30];
  const float* w_fc2    = (const float*)d_in[31];
  const float* b_fc2    = (const float*)d_in[32];
  float* out = (float*)d_out;

  const size_t SZ_XQ  = (size_t)NB * NQ * D_EMB;   // 2M elems
  const size_t SZ_KV  = (size_t)NB * NS * D_EMB;   // 16.8M elems
  const size_t SZ_W   = (size_t)FF * D_EMB;        // 16.8M elems (max weight)

  float* x1   = (float*)d_ws;
  float* x2   = x1 + SZ_XQ;
  short* h_ln = (short*)(x2 + SZ_XQ);
  short* qh   = h_ln + SZ_XQ;
  short* ctxb = qh + SZ_XQ;
  short* kh   = ctxb + SZ_XQ;
  short* vh   = kh + SZ_KV;
  short* xfb  = vh + SZ_KV;
  short* Wt   = xfb + SZ_KV;
  short* fc1b = kh;                    // alias: kh dead by MLP time

  const dim3 blk(256);
  const dim3 g_q(D_EMB / 128, (NB * NQ) / 128);    // (16, 8)
  const dim3 g_kv(D_EMB / 128, (NB * NS) / 128);   // (16, 64)
  const dim3 g_f1(FF / 128, (NB * NQ) / 128);      // (64, 8)
  const dim3 g_tw(D_EMB / 64, D_EMB / 64);         // 2048x2048 transpose
  const dim3 g_tf1(FF / 64, D_EMB / 64);           // W[2048,8192]
  const dim3 g_tf2(D_EMB / 64, FF / 64);           // W[8192,2048]
  const int  g_cvt = (int)(SZ_KV / 8 / 256);

  // ---- layer 1 ----
  cvt_kernel<<<g_cvt, blk, 0, stream>>>(xf1, xfb, (int)SZ_KV);
  ln_kernel<<<NB * NQ, blk, 0, stream>>>(x, L1[0], L1[1], h_ln);
  transpose_kernel<<<g_tw, blk, 0, stream>>>(L1[2], Wt, D_EMB, D_EMB);
  gemm_kernel<0,0><<<g_q,  blk, 0, stream>>>(h_ln, Wt, L1[3], nullptr, qh, NB * NQ, D_EMB, D_EMB);
  transpose_kernel<<<g_tw, blk, 0, stream>>>(L1[4], Wt, D_EMB, D_EMB);
  gemm_kernel<0,0><<<g_kv, blk, 0, stream>>>(xfb, Wt, L1[5], nullptr, kh, NB * NS, D_EMB, D_EMB);
  transpose_kernel<<<g_tw, blk, 0, stream>>>(L1[6], Wt, D_EMB, D_EMB);
  gemm_kernel<0,0><<<g_kv, blk, 0, stream>>>(xfb, Wt, L1[7], nullptr, vh, NB * NS, D_EMB, D_EMB);
  attn_kernel<<<NB * NH * 4, blk, 0, stream>>>(qh, kh, vh, L1[10], L1[11], ctxb);
  transpose_kernel<<<g_tw, blk, 0, stream>>>(L1[8], Wt, D_EMB, D_EMB);
  gemm_kernel<1,1><<<g_q,  blk, 0, stream>>>(ctxb, Wt, L1[9], x, x1, NB * NQ, D_EMB, D_EMB);

  // ---- layer 2 ----
  cvt_kernel<<<g_cvt, blk, 0, stream>>>(xf2, xfb, (int)SZ_KV);
  ln_kernel<<<NB * NQ, blk, 0, stream>>>(x1, L2[0], L2[1], h_ln);
  transpose_kernel<<<g_tw, blk, 0, stream>>>(L2[2], Wt, D_EMB, D_EMB);
  gemm_kernel<0,0><<<g_q,  blk, 0, stream>>>(h_ln, Wt, L2[3], nullptr, qh, NB * NQ, D_EMB, D_EMB);
  transpose_kernel<<<g_tw, blk, 0, stream>>>(L2[4], Wt, D_EMB, D_EMB);
  gemm_kernel<0,0><<<g_kv, blk, 0, stream>>>(xfb, Wt, L2[5], nullptr, kh, NB * NS, D_EMB, D_EMB);
  transpose_kernel<<<g_tw, blk, 0, stream>>>(L2[6], Wt, D_EMB, D_EMB);
  gemm_kernel<0,0><<<g_kv, blk, 0, stream>>>(xfb, Wt, L2[7], nullptr, vh, NB * NS, D_EMB, D_EMB);
  attn_kernel<<<NB * NH * 4, blk, 0, stream>>>(qh, kh, vh, L2[10], L2[11], ctxb);
  transpose_kernel<<<g_tw, blk, 0, stream>>>(L2[8], Wt, D_EMB, D_EMB);
  gemm_kernel<1,1><<<g_q,  blk, 0, stream>>>(ctxb, Wt, L2[9], x1, x2, NB * NQ, D_EMB, D_EMB);

  // ---- MLP ----
  ln_kernel<<<NB * NQ, blk, 0, stream>>>(x2, ln_mlp_s, ln_mlp_o, h_ln);
  transpose_kernel<<<g_tf1, blk, 0, stream>>>(w_fc1, Wt, D_EMB, FF);
  gemm_kernel<2,0><<<g_f1, blk, 0, stream>>>(h_ln, Wt, b_fc1, nullptr, fc1b, NB * NQ, FF, D_EMB);
  transpose_kernel<<<g_tf2, blk, 0, stream>>>(w_fc2, Wt, FF, D_EMB);
  gemm_kernel<1,1><<<g_q,  blk, 0, stream>>>(fc1b, Wt, b_fc2, x2, out, NB * NQ, D_EMB, FF);
}